// Round 11
// baseline (297.344 us; speedup 1.0000x reference)
//
#include <hip/hip_runtime.h>
#include <hip/hip_bf16.h>
#include <hip/hip_fp16.h>
#include <math.h>

#define N_NODES 50000
#define NFEAT 256
#define NHID 64
#define NHEADS 8
#define FTOT 512
#define E_TOT 1650000
#define ALPHA 0.2f
#define ALDS 264  // LDS row stride in shorts (256 + 8 pad, keeps 16B align)
#define GEMM_BLKS 782
#define SCAT_BLKS 3223
#define LOG2E 1.442695040888963f

// dst-tiled CSR: key = src*NT + (dst>>12). 13 tiles x 4096 nodes = 2MB h1 each.
#define NT 13
#define NK (N_NODES * NT)  // 650000
#define SC_ELEMS 4096      // elements per scan block (256 thr x 16)
#define NB1 159            // ceil(NK / SC_ELEMS)

typedef short s16x4 __attribute__((ext_vector_type(4)));
typedef short s16x8 __attribute__((ext_vector_type(8)));
typedef float f32x4 __attribute__((ext_vector_type(4)));
typedef float f32x2 __attribute__((ext_vector_type(2)));

__device__ __forceinline__ short f2bf(float f) {  // RNE f32->bf16
  unsigned u = __float_as_uint(f);
  unsigned r = u + 0x7fffu + ((u >> 16) & 1u);
  return (short)(r >> 16);
}

__device__ __forceinline__ unsigned char f2fp8(float f) {  // RNE f32->e4m3
  return (unsigned char)(__builtin_amdgcn_cvt_pk_fp8_f32(f, 0.f, 0, false) & 0xff);
}

// decode 8 fp8 (uint2), accumulate e*h into 4 packed-f32 accumulators
__device__ __forceinline__ void fma8_fp8(float e, uint2 u, f32x2* acc2) {
  f32x2 ev; ev[0] = e; ev[1] = e;
  acc2[0] += ev * __builtin_amdgcn_cvt_pk_f32_fp8(u.x, false);
  acc2[1] += ev * __builtin_amdgcn_cvt_pk_f32_fp8(u.x, true);
  acc2[2] += ev * __builtin_amdgcn_cvt_pk_f32_fp8(u.y, false);
  acc2[3] += ev * __builtin_amdgcn_cvt_pk_f32_fp8(u.y, true);
}

// blocks [0,512): W[h][k][j] fp32 -> Wt[h][j][k] bf16
// blocks [512,...): histogram over (src,dst-tile) keys + per-edge rank
__global__ __launch_bounds__(256) void setup_kernel(
    const float* __restrict__ W, short* __restrict__ Wt,
    const int* __restrict__ src, const int* __restrict__ dst,
    int* __restrict__ cnt, int* __restrict__ rank) {
  int b = blockIdx.x, t = threadIdx.x;
  if (b < 512) {
    int idx = b * 256 + t;
    int h = idx >> 14, r = idx & 16383, k = r >> 6, j = r & 63;
    Wt[h * 16384 + j * 256 + k] = f2bf(W[idx]);
  } else {
    int i = (b - 512) * 256 + t;
    if (i < E_TOT) {
      int key = src[i] * NT + (dst[i] >> 12);
      rank[i] = atomicAdd(&cnt[key], 1);
    }
  }
}

// scan level 1: 4096 elems/block (256 thr x 16), exclusive within block
__global__ __launch_bounds__(256) void scan1_kernel(const int* __restrict__ cnt,
                                                    int* __restrict__ offs,
                                                    int* __restrict__ bsum) {
  __shared__ int sh[256];
  int b = blockIdx.x, t = threadIdx.x;
  int base = b * SC_ELEMS + t * 16;
  int v[16];
  int s = 0;
  if (base < NK) {  // NK%16==0 so a thread is fully in or fully out
#pragma unroll
    for (int k = 0; k < 4; ++k) {
      int4 q = *reinterpret_cast<const int4*>(cnt + base + k * 4);
      v[4 * k] = q.x; v[4 * k + 1] = q.y; v[4 * k + 2] = q.z; v[4 * k + 3] = q.w;
    }
#pragma unroll
    for (int k = 0; k < 16; ++k) s += v[k];
  } else {
#pragma unroll
    for (int k = 0; k < 16; ++k) v[k] = 0;
  }
  sh[t] = s;
  __syncthreads();
  for (int o = 1; o < 256; o <<= 1) {
    int u = (t >= o) ? sh[t - o] : 0;
    __syncthreads();
    sh[t] += u;
    __syncthreads();
  }
  int run = sh[t] - s;  // exclusive base for this thread
  if (base < NK) {
#pragma unroll
    for (int k = 0; k < 16; ++k) {
      offs[base + k] = run;
      run += v[k];
    }
  }
  if (t == 255) bsum[b] = sh[255];
}

// scan level 2 + add-back: every block prefixes the NB1 block sums in LDS,
// adds its exclusive base to its 4096-element offs slice.
__global__ __launch_bounds__(256) void scan23_kernel(
    const int* __restrict__ bsum, int* __restrict__ offs) {
  __shared__ int sh[256];
  int b = blockIdx.x, t = threadIdx.x;
  int v = (t < NB1) ? bsum[t] : 0;
  sh[t] = v;
  __syncthreads();
  for (int o = 1; o < 256; o <<= 1) {
    int u = (t >= o) ? sh[t - o] : 0;
    __syncthreads();
    sh[t] += u;
    __syncthreads();
  }
  int base = (b > 0) ? sh[b - 1] : 0;
  int i0 = b * SC_ELEMS + t * 16;
  if (i0 < NK) {
#pragma unroll
    for (int k = 0; k < 16; ++k) offs[i0 + k] += base;
  }
  if (b == 0 && t == 0) offs[NK] = sh[NB1 - 1];
}

// blocks [0,GEMM_BLKS): h1 GEMM via bf16 MFMA (8 waves, wave = head).
// blocks [GEMM_BLKS,...): edst scatter into dst-tiled CSR (overlapped).
__global__ __launch_bounds__(512) void gemm_scatter_kernel(
    const float* __restrict__ x, const short* __restrict__ Wt,
    const float* __restrict__ a, unsigned char* __restrict__ h1,
    float* __restrict__ f1, float* __restrict__ f2,
    const int* __restrict__ src, const int* __restrict__ dst,
    const int* __restrict__ offsets, const int* __restrict__ rank,
    int* __restrict__ edst) {
  if (blockIdx.x >= GEMM_BLKS) {
    int i = (blockIdx.x - GEMM_BLKS) * 512 + threadIdx.x;
    if (i < E_TOT) {
      int d = dst[i];
      int key = src[i] * NT + (d >> 12);
      edst[offsets[key] + rank[i]] = d;
    }
    return;
  }
  __shared__ __align__(16) short A_s[64 * ALDS];  // 33 KB
  int bm = blockIdx.x * 64;
  int t = threadIdx.x;
  int wid = t >> 6, l = t & 63;
  int lr = l & 15, lk = l >> 4;
  int arow = t >> 3, acol = (t & 7) * 4;  // thread covers cols acol+32*i
  const short* wbase = Wt + wid * 16384 + lr * 256 + lk * 8;
  int gr = bm + arow;
  float4 xr[8];
#pragma unroll
  for (int i = 0; i < 8; ++i) {
    if (gr < N_NODES)
      xr[i] = *reinterpret_cast<const float4*>(x + (size_t)gr * NFEAT + i * 32 + acol);
    else
      xr[i] = make_float4(0.f, 0.f, 0.f, 0.f);
  }
#pragma unroll
  for (int i = 0; i < 8; ++i) {
    s16x4 v;
    v[0] = f2bf(xr[i].x); v[1] = f2bf(xr[i].y);
    v[2] = f2bf(xr[i].z); v[3] = f2bf(xr[i].w);
    *reinterpret_cast<s16x4*>(&A_s[arow * ALDS + i * 32 + acol]) = v;
  }
  __syncthreads();
  f32x4 acc[4][4] = {};
  for (int k0 = 0; k0 < NFEAT; k0 += 32) {
    s16x8 bf[4];
#pragma unroll
    for (int nj = 0; nj < 4; ++nj)
      bf[nj] = *reinterpret_cast<const s16x8*>(wbase + nj * 16 * 256 + k0);
    s16x8 af[4];
#pragma unroll
    for (int mi = 0; mi < 4; ++mi)
      af[mi] = *reinterpret_cast<const s16x8*>(
          &A_s[(mi * 16 + lr) * ALDS + k0 + lk * 8]);
#pragma unroll
    for (int mi = 0; mi < 4; ++mi)
#pragma unroll
      for (int nj = 0; nj < 4; ++nj)
        acc[mi][nj] = __builtin_amdgcn_mfma_f32_16x16x32_bf16(
            af[mi], bf[nj], acc[mi][nj], 0, 0, 0);
  }
  // store h1 (fp8 e4m3)
#pragma unroll
  for (int mi = 0; mi < 4; ++mi) {
#pragma unroll
    for (int nj = 0; nj < 4; ++nj) {
#pragma unroll
      for (int q = 0; q < 4; ++q) {
        int r = bm + mi * 16 + lk * 4 + q;
        if (r < N_NODES)
          h1[(size_t)r * FTOT + wid * 64 + nj * 16 + lr] = f2fp8(acc[mi][nj][q]);
      }
    }
  }
  // fused f1/f2 for head=wid, pre-scaled by -log2(e)
  float a1v[4], a2v[4];
#pragma unroll
  for (int nj = 0; nj < 4; ++nj) {
    a1v[nj] = a[wid * 128 + nj * 16 + lr];
    a2v[nj] = a[wid * 128 + 64 + nj * 16 + lr];
  }
#pragma unroll
  for (int mi = 0; mi < 4; ++mi) {
#pragma unroll
    for (int q = 0; q < 4; ++q) {
      float p1 = 0.f, p2 = 0.f;
#pragma unroll
      for (int nj = 0; nj < 4; ++nj) {
        p1 += acc[mi][nj][q] * a1v[nj];
        p2 += acc[mi][nj][q] * a2v[nj];
      }
      p1 += __shfl_xor(p1, 1); p2 += __shfl_xor(p2, 1);
      p1 += __shfl_xor(p1, 2); p2 += __shfl_xor(p2, 2);
      p1 += __shfl_xor(p1, 4); p2 += __shfl_xor(p2, 4);
      p1 += __shfl_xor(p1, 8); p2 += __shfl_xor(p2, 8);
      int r = bm + mi * 16 + lk * 4 + q;
      if (lr == 0 && r < N_NODES) {
        f1[r * 8 + wid] = -LOG2E * p1;
        f2[r * 8 + wid] = -LOG2E * p2;
      }
    }
  }
}

// WAVE-per-node aggregation, 4-deep gather pipeline (fp8 rows: 8B/lane).
// Edges per node are contiguous AND dst-tile-sorted -> phase-coherent
// L2-local gathers. e = exp2(min(cs, alpha*cs)), cs = f1s + f2s (pre-scaled).
__global__ __launch_bounds__(256) void aggregate_kernel(
    const unsigned char* __restrict__ h1, const float* __restrict__ f1,
    const float* __restrict__ f2, const int* __restrict__ offsets,
    const int* __restrict__ edst, const float* __restrict__ W_out,
    float* __restrict__ hout) {
  int wv = __builtin_amdgcn_readfirstlane(threadIdx.x >> 6);
  int n = blockIdx.x * 4 + wv;
  int l = threadIdx.x & 63;
  int head = l >> 3;
  int beg = offsets[n * NT], end = offsets[n * NT + NT];
  float F = f1[n * 8 + head];
  f32x2 acc2[4] = {};
  float rs = 0.f;
  int j = beg;
  for (; j + 3 < end; j += 4) {
    int d0 = edst[j], d1 = edst[j + 1], d2 = edst[j + 2], d3 = edst[j + 3];
    uint2 u0 = *reinterpret_cast<const uint2*>(h1 + (size_t)d0 * FTOT + l * 8);
    uint2 u1 = *reinterpret_cast<const uint2*>(h1 + (size_t)d1 * FTOT + l * 8);
    uint2 u2 = *reinterpret_cast<const uint2*>(h1 + (size_t)d2 * FTOT + l * 8);
    uint2 u3 = *reinterpret_cast<const uint2*>(h1 + (size_t)d3 * FTOT + l * 8);
    float g0 = f2[d0 * 8 + head];
    float g1 = f2[d1 * 8 + head];
    float g2 = f2[d2 * 8 + head];
    float g3 = f2[d3 * 8 + head];
    float c0 = F + g0, c1 = F + g1, c2 = F + g2, c3 = F + g3;
    float e0 = __builtin_amdgcn_exp2f(fminf(c0, ALPHA * c0));
    float e1 = __builtin_amdgcn_exp2f(fminf(c1, ALPHA * c1));
    float e2 = __builtin_amdgcn_exp2f(fminf(c2, ALPHA * c2));
    float e3 = __builtin_amdgcn_exp2f(fminf(c3, ALPHA * c3));
    rs += (e0 + e1) + (e2 + e3);
    fma8_fp8(e0, u0, acc2);
    fma8_fp8(e1, u1, acc2);
    fma8_fp8(e2, u2, acc2);
    fma8_fp8(e3, u3, acc2);
  }
  for (; j < end; ++j) {
    int d = edst[j];
    uint2 u = *reinterpret_cast<const uint2*>(h1 + (size_t)d * FTOT + l * 8);
    float cs = F + f2[d * 8 + head];
    float e = __builtin_amdgcn_exp2f(fminf(cs, ALPHA * cs));
    rs += e;
    fma8_fp8(e, u, acc2);
  }
  // epilogue: elu(acc/rs) dot W_out, all in-wave
  float inv = 1.f / rs;
  float v = 0.f;
  const float* wop = W_out + l * 8;
#pragma unroll
  for (int k = 0; k < 4; ++k) {
#pragma unroll
    for (int q = 0; q < 2; ++q) {
      float o = acc2[k][q] * inv;
      o = (o > 0.f) ? o : expm1f(o);
      v += o * wop[k * 2 + q];
    }
  }
#pragma unroll
  for (int o = 32; o > 0; o >>= 1) v += __shfl_down(v, o);
  if (l == 0) hout[n] = v;
}

// layer-2 edge phase + elu + sigmoid. 4 nodes/block, one wave each.
__global__ __launch_bounds__(256) void layer2_kernel(
    const int* __restrict__ offsets, const int* __restrict__ edst,
    const float* __restrict__ hout, const float* __restrict__ a_out,
    float* __restrict__ out) {
  int wv = __builtin_amdgcn_readfirstlane(threadIdx.x >> 6);
  int n = blockIdx.x * 4 + wv;
  int l = threadIdx.x & 63;
  float a0 = a_out[0], a1 = a_out[1];
  int beg = offsets[n * NT], end = offsets[n * NT + NT];
  float f1v = hout[n] * a0;
  float rs = 0.f, num = 0.f;
  for (int j = beg + l; j < end; j += 64) {
    int d = edst[j];
    float hd = hout[d];
    float s = f1v + a1 * hd;
    float lk = fmaxf(s, ALPHA * s);
    float e = __builtin_amdgcn_exp2f(-LOG2E * lk);
    rs += e;
    num += e * hd;
  }
#pragma unroll
  for (int o = 32; o > 0; o >>= 1) {
    rs += __shfl_down(rs, o);
    num += __shfl_down(num, o);
  }
  if (l == 0) {
    float o_ = num / rs;
    float el = (o_ > 0.f) ? o_ : expm1f(o_);
    out[n] = 1.f / (1.f + __builtin_amdgcn_exp2f(-LOG2E * el));
  }
}

extern "C" void kernel_launch(void* const* d_in, const int* in_sizes, int n_in,
                              void* d_out, int out_size, void* d_ws, size_t ws_size,
                              hipStream_t stream) {
  const float* x = (const float*)d_in[0];
  const int* ei = (const int*)d_in[1];
  const float* W = (const float*)d_in[2];
  const float* a = (const float*)d_in[3];
  const float* W_out = (const float*)d_in[4];
  const float* a_out = (const float*)d_in[5];
  float* out = (float*)d_out;
  const int* src = ei;
  const int* dst = ei + E_TOT;

  char* p = (char*)d_ws;
  auto carve = [&](size_t bytes) {
    char* r = p;
    p += (bytes + 255) & ~(size_t)255;
    return r;
  };
  unsigned char* h1 = (unsigned char*)carve((size_t)N_NODES * FTOT);
  float* f1 = (float*)carve((size_t)N_NODES * 8 * 4);
  float* f2 = (float*)carve((size_t)N_NODES * 8 * 4);
  int* offsets = (int*)carve((size_t)(NK + 1) * 4);
  int* cnt = (int*)carve((size_t)NK * 4);
  int* rank = (int*)carve((size_t)E_TOT * 4);
  int* edst = (int*)carve((size_t)E_TOT * 4);
  int* bsum = (int*)carve((size_t)NB1 * 4);
  short* Wt = (short*)carve((size_t)NHEADS * NFEAT * NHID * 2);
  float* hout = (float*)carve((size_t)N_NODES * 4);

  hipMemsetAsync(cnt, 0, (size_t)NK * 4, stream);

  setup_kernel<<<512 + 6446, 256, 0, stream>>>(W, Wt, src, dst, cnt, rank);
  scan1_kernel<<<NB1, 256, 0, stream>>>(cnt, offsets, bsum);
  scan23_kernel<<<NB1, 256, 0, stream>>>(bsum, offsets);
  gemm_scatter_kernel<<<GEMM_BLKS + SCAT_BLKS, 512, 0, stream>>>(
      x, Wt, a, h1, f1, f2, src, dst, offsets, rank, edst);
  aggregate_kernel<<<12500, 256, 0, stream>>>(h1, f1, f2, offsets, edst, W_out, hout);
  layer2_kernel<<<12500, 256, 0, stream>>>(offsets, edst, hout, a_out, out);
}

// Round 12
// 286.992 us; speedup vs baseline: 1.0361x; 1.0361x over previous
//
#include <hip/hip_runtime.h>
#include <hip/hip_bf16.h>
#include <hip/hip_fp16.h>
#include <math.h>

#define N_NODES 50000
#define NFEAT 256
#define NHID 64
#define NHEADS 8
#define FTOT 512
#define E_TOT 1650000
#define ALPHA 0.2f
#define NB_SCAN 196
#define ALDS 264  // LDS row stride in shorts (256 + 8 pad, keeps 16B align)
#define GEMM_BLKS 782
#define HIST_BLKS 3223   // ceil(E_TOT/512)
#define LOG2E 1.442695040888963f

typedef short s16x4 __attribute__((ext_vector_type(4)));
typedef short s16x8 __attribute__((ext_vector_type(8)));
typedef float f32x4 __attribute__((ext_vector_type(4)));
typedef float f32x2 __attribute__((ext_vector_type(2)));

__device__ __forceinline__ short f2bf(float f) {  // RNE f32->bf16
  unsigned u = __float_as_uint(f);
  unsigned r = u + 0x7fffu + ((u >> 16) & 1u);
  return (short)(r >> 16);
}

__device__ __forceinline__ unsigned char f2fp8(float f) {  // RNE f32->e4m3
  return (unsigned char)(__builtin_amdgcn_cvt_pk_fp8_f32(f, 0.f, 0, false) & 0xff);
}

// decode 8 fp8 (uint2), accumulate e*h into 4 packed-f32 accumulators
__device__ __forceinline__ void fma8_fp8(float e, uint2 u, f32x2* acc2) {
  f32x2 ev; ev[0] = e; ev[1] = e;
  acc2[0] += ev * __builtin_amdgcn_cvt_pk_f32_fp8(u.x, false);
  acc2[1] += ev * __builtin_amdgcn_cvt_pk_f32_fp8(u.x, true);
  acc2[2] += ev * __builtin_amdgcn_cvt_pk_f32_fp8(u.y, false);
  acc2[3] += ev * __builtin_amdgcn_cvt_pk_f32_fp8(u.y, true);
}

// blocks [0,512): W[h][k][j] fp32 -> Wt[h][j][k] bf16
// blocks [512,712): zero cnt
__global__ __launch_bounds__(256) void wconv_zero_kernel(
    const float* __restrict__ W, short* __restrict__ Wt, int* __restrict__ cnt) {
  int b = blockIdx.x, t = threadIdx.x;
  if (b < 512) {
    int idx = b * 256 + t;
    int h = idx >> 14, r = idx & 16383, k = r >> 6, j = r & 63;
    Wt[h * 16384 + j * 256 + k] = f2bf(W[idx]);
  } else {
    int i = (b - 512) * 256 + t;
    if (i < N_NODES) cnt[i] = 0;
  }
}

// blocks [0,GEMM_BLKS): h1 GEMM via bf16 MFMA (8 waves, wave = head).
// blocks [GEMM_BLKS,...): src histogram + per-edge rank (independent of GEMM;
// its atomic latency hides under the GEMM's occupancy).
__global__ __launch_bounds__(512) void gemm_hist_kernel(
    const float* __restrict__ x, const short* __restrict__ Wt,
    const float* __restrict__ a, unsigned char* __restrict__ h1,
    float* __restrict__ f1, float* __restrict__ f2,
    const int* __restrict__ src, int* __restrict__ cnt,
    int* __restrict__ rank) {
  if (blockIdx.x >= GEMM_BLKS) {
    int i = (blockIdx.x - GEMM_BLKS) * 512 + threadIdx.x;
    if (i < E_TOT) rank[i] = atomicAdd(&cnt[src[i]], 1);
    return;
  }
  __shared__ __align__(16) short A_s[64 * ALDS];  // 33 KB
  int bm = blockIdx.x * 64;
  int t = threadIdx.x;
  int wid = t >> 6, l = t & 63;
  int lr = l & 15, lk = l >> 4;
  int arow = t >> 3, acol = (t & 7) * 4;  // thread covers cols acol+32*i
  const short* wbase = Wt + wid * 16384 + lr * 256 + lk * 8;
  int gr = bm + arow;
  float4 xr[8];
#pragma unroll
  for (int i = 0; i < 8; ++i) {
    if (gr < N_NODES)
      xr[i] = *reinterpret_cast<const float4*>(x + (size_t)gr * NFEAT + i * 32 + acol);
    else
      xr[i] = make_float4(0.f, 0.f, 0.f, 0.f);
  }
#pragma unroll
  for (int i = 0; i < 8; ++i) {
    s16x4 v;
    v[0] = f2bf(xr[i].x); v[1] = f2bf(xr[i].y);
    v[2] = f2bf(xr[i].z); v[3] = f2bf(xr[i].w);
    *reinterpret_cast<s16x4*>(&A_s[arow * ALDS + i * 32 + acol]) = v;
  }
  __syncthreads();
  f32x4 acc[4][4] = {};
  for (int k0 = 0; k0 < NFEAT; k0 += 32) {
    s16x8 bf[4];
#pragma unroll
    for (int nj = 0; nj < 4; ++nj)
      bf[nj] = *reinterpret_cast<const s16x8*>(wbase + nj * 16 * 256 + k0);
    s16x8 af[4];
#pragma unroll
    for (int mi = 0; mi < 4; ++mi)
      af[mi] = *reinterpret_cast<const s16x8*>(
          &A_s[(mi * 16 + lr) * ALDS + k0 + lk * 8]);
#pragma unroll
    for (int mi = 0; mi < 4; ++mi)
#pragma unroll
      for (int nj = 0; nj < 4; ++nj)
        acc[mi][nj] = __builtin_amdgcn_mfma_f32_16x16x32_bf16(
            af[mi], bf[nj], acc[mi][nj], 0, 0, 0);
  }
  // store h1 (fp8 e4m3)
#pragma unroll
  for (int mi = 0; mi < 4; ++mi) {
#pragma unroll
    for (int nj = 0; nj < 4; ++nj) {
#pragma unroll
      for (int q = 0; q < 4; ++q) {
        int r = bm + mi * 16 + lk * 4 + q;
        if (r < N_NODES)
          h1[(size_t)r * FTOT + wid * 64 + nj * 16 + lr] = f2fp8(acc[mi][nj][q]);
      }
    }
  }
  // fused f1/f2 for head=wid, pre-scaled by -log2(e)
  float a1v[4], a2v[4];
#pragma unroll
  for (int nj = 0; nj < 4; ++nj) {
    a1v[nj] = a[wid * 128 + nj * 16 + lr];
    a2v[nj] = a[wid * 128 + 64 + nj * 16 + lr];
  }
#pragma unroll
  for (int mi = 0; mi < 4; ++mi) {
#pragma unroll
    for (int q = 0; q < 4; ++q) {
      float p1 = 0.f, p2 = 0.f;
#pragma unroll
      for (int nj = 0; nj < 4; ++nj) {
        p1 += acc[mi][nj][q] * a1v[nj];
        p2 += acc[mi][nj][q] * a2v[nj];
      }
      p1 += __shfl_xor(p1, 1); p2 += __shfl_xor(p2, 1);
      p1 += __shfl_xor(p1, 2); p2 += __shfl_xor(p2, 2);
      p1 += __shfl_xor(p1, 4); p2 += __shfl_xor(p2, 4);
      p1 += __shfl_xor(p1, 8); p2 += __shfl_xor(p2, 8);
      int r = bm + mi * 16 + lk * 4 + q;
      if (lr == 0 && r < N_NODES) {
        f1[r * 8 + wid] = -LOG2E * p1;
        f2[r * 8 + wid] = -LOG2E * p2;
      }
    }
  }
}

__global__ __launch_bounds__(256) void scan1_kernel(const int* __restrict__ cnt,
                                                    int* __restrict__ offs,
                                                    int* __restrict__ bsum) {
  __shared__ int sh[256];
  int b = blockIdx.x, t = threadIdx.x, i = b * 256 + t;
  int v = (i < N_NODES) ? cnt[i] : 0;
  sh[t] = v;
  __syncthreads();
  for (int o = 1; o < 256; o <<= 1) {
    int u = (t >= o) ? sh[t - o] : 0;
    __syncthreads();
    sh[t] += u;
    __syncthreads();
  }
  if (i < N_NODES) offs[i] = sh[t] - v;
  if (t == 255) bsum[b] = sh[255];
}

// merged scan2+scan3: every block prefixes the 196 block sums in LDS,
// then adds its own exclusive base to its offs slice.
__global__ __launch_bounds__(256) void scan23_kernel(
    const int* __restrict__ bsum, int* __restrict__ offs) {
  __shared__ int sh[256];
  int b = blockIdx.x, t = threadIdx.x;
  int v = (t < NB_SCAN) ? bsum[t] : 0;
  sh[t] = v;
  __syncthreads();
  for (int o = 1; o < 256; o <<= 1) {
    int u = (t >= o) ? sh[t - o] : 0;
    __syncthreads();
    sh[t] += u;
    __syncthreads();
  }
  int base = (b > 0) ? sh[b - 1] : 0;
  int i = b * 256 + t;
  if (i < N_NODES) offs[i] += base;
  if (b == 0 && t == 0) offs[N_NODES] = sh[NB_SCAN - 1];
}

// edst[offsets[s] + rank[i]] = dst[i]  (no atomics)
__global__ __launch_bounds__(512) void scatter_kernel(
    const int* __restrict__ src, const int* __restrict__ dst,
    const int* __restrict__ offsets, const int* __restrict__ rank,
    int* __restrict__ edst) {
  int i = blockIdx.x * 512 + threadIdx.x;
  if (i < E_TOT) {
    int s = src[i];
    edst[offsets[s] + rank[i]] = dst[i];
  }
}

// WAVE-per-node aggregation, 4-deep gather pipeline (fp8 rows: 8B/lane).
// e = exp2(min(cs, alpha*cs)), cs = f1s + f2s (both pre-scaled by -log2e).
__global__ __launch_bounds__(256) void aggregate_kernel(
    const unsigned char* __restrict__ h1, const float* __restrict__ f1,
    const float* __restrict__ f2, const int* __restrict__ offsets,
    const int* __restrict__ edst, const float* __restrict__ W_out,
    float* __restrict__ hout) {
  int wv = __builtin_amdgcn_readfirstlane(threadIdx.x >> 6);
  int n = blockIdx.x * 4 + wv;
  int l = threadIdx.x & 63;
  int head = l >> 3;
  int beg = offsets[n], end = offsets[n + 1];
  float F = f1[n * 8 + head];
  f32x2 acc2[4] = {};
  float rs = 0.f;
  int j = beg;
  for (; j + 3 < end; j += 4) {
    int d0 = edst[j], d1 = edst[j + 1], d2 = edst[j + 2], d3 = edst[j + 3];
    uint2 u0 = *reinterpret_cast<const uint2*>(h1 + (size_t)d0 * FTOT + l * 8);
    uint2 u1 = *reinterpret_cast<const uint2*>(h1 + (size_t)d1 * FTOT + l * 8);
    uint2 u2 = *reinterpret_cast<const uint2*>(h1 + (size_t)d2 * FTOT + l * 8);
    uint2 u3 = *reinterpret_cast<const uint2*>(h1 + (size_t)d3 * FTOT + l * 8);
    float g0 = f2[d0 * 8 + head];
    float g1 = f2[d1 * 8 + head];
    float g2 = f2[d2 * 8 + head];
    float g3 = f2[d3 * 8 + head];
    float c0 = F + g0, c1 = F + g1, c2 = F + g2, c3 = F + g3;
    float e0 = __builtin_amdgcn_exp2f(fminf(c0, ALPHA * c0));
    float e1 = __builtin_amdgcn_exp2f(fminf(c1, ALPHA * c1));
    float e2 = __builtin_amdgcn_exp2f(fminf(c2, ALPHA * c2));
    float e3 = __builtin_amdgcn_exp2f(fminf(c3, ALPHA * c3));
    rs += (e0 + e1) + (e2 + e3);
    fma8_fp8(e0, u0, acc2);
    fma8_fp8(e1, u1, acc2);
    fma8_fp8(e2, u2, acc2);
    fma8_fp8(e3, u3, acc2);
  }
  for (; j < end; ++j) {
    int d = edst[j];
    uint2 u = *reinterpret_cast<const uint2*>(h1 + (size_t)d * FTOT + l * 8);
    float cs = F + f2[d * 8 + head];
    float e = __builtin_amdgcn_exp2f(fminf(cs, ALPHA * cs));
    rs += e;
    fma8_fp8(e, u, acc2);
  }
  // epilogue: elu(acc/rs) dot W_out, all in-wave
  float inv = 1.f / rs;
  float v = 0.f;
  const float* wop = W_out + l * 8;
#pragma unroll
  for (int k = 0; k < 4; ++k) {
#pragma unroll
    for (int q = 0; q < 2; ++q) {
      float o = acc2[k][q] * inv;
      o = (o > 0.f) ? o : expm1f(o);
      v += o * wop[k * 2 + q];
    }
  }
#pragma unroll
  for (int o = 32; o > 0; o >>= 1) v += __shfl_down(v, o);
  if (l == 0) hout[n] = v;
}

// layer-2 edge phase + elu + sigmoid. 4 nodes/block, one wave each.
__global__ __launch_bounds__(256) void layer2_kernel(
    const int* __restrict__ offsets, const int* __restrict__ edst,
    const float* __restrict__ hout, const float* __restrict__ a_out,
    float* __restrict__ out) {
  int wv = __builtin_amdgcn_readfirstlane(threadIdx.x >> 6);
  int n = blockIdx.x * 4 + wv;
  int l = threadIdx.x & 63;
  float a0 = a_out[0], a1 = a_out[1];
  int beg = offsets[n], end = offsets[n + 1];
  float f1v = hout[n] * a0;
  float rs = 0.f, num = 0.f;
  for (int j = beg + l; j < end; j += 64) {
    int d = edst[j];
    float hd = hout[d];
    float s = f1v + a1 * hd;
    float lk = fmaxf(s, ALPHA * s);
    float e = __builtin_amdgcn_exp2f(-LOG2E * lk);
    rs += e;
    num += e * hd;
  }
#pragma unroll
  for (int o = 32; o > 0; o >>= 1) {
    rs += __shfl_down(rs, o);
    num += __shfl_down(num, o);
  }
  if (l == 0) {
    float o_ = num / rs;
    float el = (o_ > 0.f) ? o_ : expm1f(o_);
    out[n] = 1.f / (1.f + __builtin_amdgcn_exp2f(-LOG2E * el));
  }
}

extern "C" void kernel_launch(void* const* d_in, const int* in_sizes, int n_in,
                              void* d_out, int out_size, void* d_ws, size_t ws_size,
                              hipStream_t stream) {
  const float* x = (const float*)d_in[0];
  const int* ei = (const int*)d_in[1];
  const float* W = (const float*)d_in[2];
  const float* a = (const float*)d_in[3];
  const float* W_out = (const float*)d_in[4];
  const float* a_out = (const float*)d_in[5];
  float* out = (float*)d_out;
  const int* src = ei;
  const int* dst = ei + E_TOT;

  char* p = (char*)d_ws;
  auto carve = [&](size_t bytes) {
    char* r = p;
    p += (bytes + 255) & ~(size_t)255;
    return r;
  };
  unsigned char* h1 = (unsigned char*)carve((size_t)N_NODES * FTOT);
  float* f1 = (float*)carve((size_t)N_NODES * 8 * 4);
  float* f2 = (float*)carve((size_t)N_NODES * 8 * 4);
  int* offsets = (int*)carve((size_t)(N_NODES + 1) * 4);
  int* cnt = (int*)carve((size_t)N_NODES * 4);
  int* rank = (int*)carve((size_t)E_TOT * 4);
  int* edst = (int*)carve((size_t)E_TOT * 4);
  int* bsum = (int*)carve((size_t)NB_SCAN * 4);
  short* Wt = (short*)carve((size_t)NHEADS * NFEAT * NHID * 2);
  float* hout = (float*)carve((size_t)N_NODES * 4);

  wconv_zero_kernel<<<712, 256, 0, stream>>>(W, Wt, cnt);
  gemm_hist_kernel<<<GEMM_BLKS + HIST_BLKS, 512, 0, stream>>>(
      x, Wt, a, h1, f1, f2, src, cnt, rank);
  scan1_kernel<<<NB_SCAN, 256, 0, stream>>>(cnt, offsets, bsum);
  scan23_kernel<<<NB_SCAN, 256, 0, stream>>>(bsum, offsets);
  scatter_kernel<<<HIST_BLKS, 512, 0, stream>>>(src, dst, offsets, rank, edst);
  aggregate_kernel<<<12500, 256, 0, stream>>>(h1, f1, f2, offsets, edst, W_out, hout);
  layer2_kernel<<<12500, 256, 0, stream>>>(offsets, edst, hout, a_out, out);
}